// Round 10
// baseline (116.534 us; speedup 1.0000x reference)
//
#include <hip/hip_runtime.h>
#include <math.h>

#define DM 512
#define LSEQ 8192
#define NV 8
#define TOK 1608
#define BROWS 32     // patch rows per block
#define NTHR 256     // 4 waves; wave = 8 rows x 256 cols; thread = 8r x 4c

typedef _Float16 h2 __attribute__((ext_vector_type(2)));
typedef float f4n __attribute__((ext_vector_type(4)));   // native float4 for builtins

// Heavy-first segment order (pl=128 first). seg -> v: {6,7,4,5,2,3,0,1}
__device__ __constant__ int c_segv[8]   = {6, 7, 4, 5, 2, 3, 0, 1};
// blocks/seg = 2 col-halves * 32 batches * (n_p/32): 64,64,256,256,256,256,1024,1024
__device__ __constant__ int c_cum[9]    = {0, 64, 128, 384, 640, 896, 1152, 2176, 3200};
__device__ __constant__ int c_lgch[8]   = {0, 0, 2, 2, 2, 2, 4, 4};   // log2(chunks/batch)
// indexed by v:
__device__ __constant__ int c_tokoff[8] = {0, 513, 1026, 1155, 1284, 1413, 1542, 1575};
__device__ __constant__ int c_np[8]     = {512, 512, 128, 128, 128, 128, 32, 32};
__device__ __constant__ int c_pl[8]     = {16, 16, 32, 32, 64, 64, 128, 128};
__device__ __constant__ int c_sf[8]     = {1, 1, 2, 2, 1, 1, 2, 2};
// packed-half2-weight word offsets within d_ws per v; pe occupies words [0,262144)
__device__ __constant__ int c_wtoff[8]  = {262144, 262144, 266240, 266240,
                                           274432, 274432, 290816, 290816};

__device__ __forceinline__ float fdot2f(h2 a, h2 b, float c) {
#if __has_builtin(__builtin_amdgcn_fdot2)
    return __builtin_amdgcn_fdot2(a, b, c, false);
#else
    return fmaf((float)a.y, (float)b.y, fmaf((float)a.x, (float)b.x, c));
#endif
}
__device__ __forceinline__ h2 bch2(unsigned u) { return __builtin_bit_cast(h2, u); }

__device__ __forceinline__ void nt_store4(float* p, float4 v) {
#if __has_builtin(__builtin_nontemporal_store)
    f4n t; t.x = v.x; t.y = v.y; t.z = v.z; t.w = v.w;
    __builtin_nontemporal_store(t, reinterpret_cast<f4n*>(p));
#else
    *reinterpret_cast<float4*>(p) = v;
#endif
}

// ---------------------------------------------------------------------------
// Setup: blocks [0,512) build pe[512][512] fp32 (numpy-matched sinusoidal,
// fast-math trig: args <= 82 revolutions, err ~5e-5 << 0.137 threshold);
// blocks [512,632) pack transposed fp16 weights wt_h[k2][512] (half2 words).
// ---------------------------------------------------------------------------
__global__ __launch_bounds__(512) void setup_kernel(
    const float* __restrict__ w16, const float* __restrict__ w32,
    const float* __restrict__ w64, const float* __restrict__ w128,
    float* __restrict__ ws)
{
    int bid = blockIdx.x;
    int d = threadIdx.x;
    if (bid < 512) {
        int idx = bid * 512 + d;
        int i = idx >> 9;
        int dd = idx & (DM - 1);
        const float c = -9.210340371976184f / 512.0f;  // -ln(10000)/D
        float div = __expf((float)(dd & ~1) * c);
        float ang = (float)i * div;
        ws[idx] = (dd & 1) ? __cosf(ang) : __sinf(ang);
        return;
    }
    int j = bid - 512;                 // 120 half2-rows across the 4 matrices
    const float* w; int pl, k2, off;
    if (j < 8)       { w = w16;  pl = 16;  k2 = j;      off = 262144; }
    else if (j < 24) { w = w32;  pl = 32;  k2 = j - 8;  off = 266240; }
    else if (j < 56) { w = w64;  pl = 64;  k2 = j - 24; off = 274432; }
    else             { w = w128; pl = 128; k2 = j - 56; off = 290816; }
    float2 p = *reinterpret_cast<const float2*>(w + (size_t)d * pl + 2 * k2);
    h2 h; h.x = (_Float16)p.x; h.y = (_Float16)p.y;
    reinterpret_cast<unsigned*>(ws)[off + k2 * DM + d] = __builtin_bit_cast(unsigned, h);
}

// 4-col dot update for row r with patch half2 P and W quad X (cols c0..c0+3)
#define DOT4(r, P, X)                                           \
    acc[r][0] = fdot2f(P, bch2((X).x), acc[r][0]);              \
    acc[r][1] = fdot2f(P, bch2((X).y), acc[r][1]);              \
    acc[r][2] = fdot2f(P, bch2((X).z), acc[r][2]);              \
    acc[r][3] = fdot2f(P, bch2((X).w), acc[r][3]);

// ---------------------------------------------------------------------------
// Main kernel. Blocks [0,3200): 32 rows x 256 cols (col-half h = local&1);
// thread = 8 rows x 4 cols, fp16 dot2, fp32 epilogue. [3200,3208): global toks.
// K loop: 8-k outer iterations; 4-row W group (4 x uint4) prefetched one FULL
// iteration (~256 issue cyc >= L2 latency) ahead.
// ---------------------------------------------------------------------------
__global__ __launch_bounds__(NTHR, 5) void patch_embed_kernel(
    const float* __restrict__ x,
    const float* __restrict__ b16,  const float* __restrict__ b32,
    const float* __restrict__ b64,  const float* __restrict__ b128,
    const float* __restrict__ glb,  const float* __restrict__ chan,
    const float* __restrict__ ws,   float* __restrict__ out)
{
    extern __shared__ float ldsf[];              // 32 rows * pl/2 half2 words, <= 8 KB
    unsigned* ldsu = reinterpret_cast<unsigned*>(ldsf);
    int bid = blockIdx.x;
    const int tid = threadIdx.x;

    if (bid >= 3200) {                           // global-token rows (8 blocks)
        int v = bid - 3200;
        int d2 = tid << 1;
        float2 g = *reinterpret_cast<const float2*>(glb + d2);
        float2 c = *reinterpret_cast<const float2*>(chan + v * DM + d2);
        float2 o; o.x = g.x + c.x; o.y = g.y + c.y;
        int row0 = c_tokoff[v] + c_np[v];
        for (int b = 0; b < 32; ++b)
            *reinterpret_cast<float2*>(out + ((size_t)(b * TOK + row0)) * DM + d2) = o;
        return;
    }

    // ---- block -> (v, h, b, chunk), block-uniform scalar work ----
    int seg = 0;
    while (bid >= c_cum[seg + 1]) ++seg;
    int local = bid - c_cum[seg];
    int v = c_segv[seg];
    int h = local & 1;                           // column half
    int rest = local >> 1;
    int lg = c_lgch[seg];
    int b = rest >> lg;
    int chunk = rest & ((1 << lg) - 1);
    const int pl = c_pl[v];
    const int sf = c_sf[v];
    const int pl2 = pl >> 1;
    const int i0 = chunk * BROWS;

    // ---- stage 32 packed patches into LDS as half2 (sampling folded) ----
    const int ne2 = (BROWS * pl) >> 1;           // half2 words
    const float* xb = x + ((size_t)b * NV + v) * LSEQ + (size_t)i0 * (pl * sf);
    if (sf == 1) {
        for (int t = tid; t < (ne2 >> 1); t += NTHR) {   // t = one float4 = 2 words
            float4 q = *reinterpret_cast<const float4*>(xb + 4 * t);
            h2 a; a.x = (_Float16)q.x; a.y = (_Float16)q.y;
            h2 c; c.x = (_Float16)q.z; c.y = (_Float16)q.w;
            uint2 o; o.x = __builtin_bit_cast(unsigned, a);
            o.y = __builtin_bit_cast(unsigned, c);
            *reinterpret_cast<uint2*>(ldsu + 2 * t) = o;
        }
    } else {
        for (int p = tid; p < ne2; p += NTHR) {          // one word per float4
            float4 q = *reinterpret_cast<const float4*>(xb + 4 * p);
            h2 a; a.x = (_Float16)q.x; a.y = (_Float16)q.z;
            ldsu[p] = __builtin_bit_cast(unsigned, a);
        }
    }
    __syncthreads();

    // ---- per-thread geometry ----
    const int lane = tid & 63;
    const int wv   = tid >> 6;                   // wave -> rows [8wv, 8wv+8)
    const int c0   = (h << 8) + (lane << 2);     // 4 consecutive cols in half h
    const unsigned* prow = ldsu + (wv * 8) * pl2;
    const unsigned* wtv  = reinterpret_cast<const unsigned*>(ws) + c_wtoff[v];

    float acc[8][4];
#pragma unroll
    for (int r = 0; r < 8; ++r)
#pragma unroll
        for (int c = 0; c < 4; ++c) acc[r][c] = 0.f;

    // ---- K loop: 8 k (4 k2-rows) per iter; W group prefetched 1 iter ahead --
    uint4 wc0 = *reinterpret_cast<const uint4*>(wtv + 0 * DM + c0);
    uint4 wc1 = *reinterpret_cast<const uint4*>(wtv + 1 * DM + c0);
    uint4 wc2 = *reinterpret_cast<const uint4*>(wtv + 2 * DM + c0);
    uint4 wc3 = *reinterpret_cast<const uint4*>(wtv + 3 * DM + c0);

#pragma unroll 2
    for (int k4 = 0; k4 < pl2; k4 += 4) {
        uint4 wn0, wn1, wn2, wn3;
        const bool more = (k4 + 4 < pl2);
        if (more) {
            const unsigned* wp = wtv + (size_t)(k4 + 4) * DM + c0;
            wn0 = *reinterpret_cast<const uint4*>(wp);
            wn1 = *reinterpret_cast<const uint4*>(wp + DM);
            wn2 = *reinterpret_cast<const uint4*>(wp + 2 * DM);
            wn3 = *reinterpret_cast<const uint4*>(wp + 3 * DM);
        }
        // half 1: k2 = k4, k4+1
        {
            uint2 pr[8];
#pragma unroll
            for (int r = 0; r < 8; ++r)
                pr[r] = *reinterpret_cast<const uint2*>(prow + r * pl2 + k4);
#pragma unroll
            for (int r = 0; r < 8; ++r) {
                DOT4(r, bch2(pr[r].x), wc0)
                DOT4(r, bch2(pr[r].y), wc1)
            }
        }
        // half 2: k2 = k4+2, k4+3
        {
            uint2 pr[8];
#pragma unroll
            for (int r = 0; r < 8; ++r)
                pr[r] = *reinterpret_cast<const uint2*>(prow + r * pl2 + k4 + 2);
#pragma unroll
            for (int r = 0; r < 8; ++r) {
                DOT4(r, bch2(pr[r].x), wc2)
                DOT4(r, bch2(pr[r].y), wc3)
            }
        }
        if (more) { wc0 = wn0; wc1 = wn1; wc2 = wn2; wc3 = wn3; }
    }

    // ---- fp32 epilogue: + bias + channel + pe, nontemporal float4 stores ----
    const float* bias = (pl == 16) ? b16 : (pl == 32) ? b32 : (pl == 64) ? b64 : b128;
    float4 bc;
    {
        float4 ba = *reinterpret_cast<const float4*>(bias + c0);
        float4 ca = *reinterpret_cast<const float4*>(chan + v * DM + c0);
        bc.x = ba.x + ca.x; bc.y = ba.y + ca.y;
        bc.z = ba.z + ca.z; bc.w = ba.w + ca.w;
    }

    const int row0 = i0 + wv * 8;
    float* ob = out + ((size_t)(b * TOK + c_tokoff[v] + row0)) * DM + c0;
    const float* pb = ws /*pe*/ + (size_t)row0 * DM + c0;
#pragma unroll
    for (int r = 0; r < 8; ++r) {
        float4 pA = *reinterpret_cast<const float4*>(pb + (size_t)r * DM);
        float4 o;
        o.x = acc[r][0] + bc.x + pA.x;
        o.y = acc[r][1] + bc.y + pA.y;
        o.z = acc[r][2] + bc.z + pA.z;
        o.w = acc[r][3] + bc.w + pA.w;
        nt_store4(ob + (size_t)r * DM, o);
    }
}

extern "C" void kernel_launch(void* const* d_in, const int* in_sizes, int n_in,
                              void* d_out, int out_size, void* d_ws, size_t ws_size,
                              hipStream_t stream) {
    const float* x    = (const float*)d_in[0];
    const float* w16  = (const float*)d_in[1];
    const float* b16  = (const float*)d_in[2];
    const float* w32  = (const float*)d_in[3];
    const float* b32  = (const float*)d_in[4];
    const float* w64  = (const float*)d_in[5];
    const float* b64  = (const float*)d_in[6];
    const float* w128 = (const float*)d_in[7];
    const float* b128 = (const float*)d_in[8];
    const float* glb  = (const float*)d_in[9];
    const float* chan = (const float*)d_in[10];
    float* out = (float*)d_out;
    float* ws  = (float*)d_ws;   // pe fp32 [0,262144) + packed fp16 wt -> 1.29 MB

    hipLaunchKernelGGL(setup_kernel, dim3(632), dim3(512), 0, stream,
                       w16, w32, w64, w128, ws);
    hipLaunchKernelGGL(patch_embed_kernel, dim3(3208), dim3(NTHR),
                       BROWS * 64 * sizeof(unsigned),   // 8 KB dynamic LDS (pl=128)
                       stream,
                       x, b16, b32, b64, b128, glb, chan, ws, out);
}

// Round 12
// 50.056 us; speedup vs baseline: 2.3281x; 2.3281x over previous
//
#include <hip/hip_runtime.h>
#include <math.h>

#define DM 512
#define LSEQ 8192
#define NV 8
#define TOK 1608
#define BROWS 32     // patch rows per block
#define NTHR 256     // 4 waves; wave = 8 rows x 256 cols; thread = 8r x 4c

typedef _Float16 h2 __attribute__((ext_vector_type(2)));
typedef float f4n __attribute__((ext_vector_type(4)));   // native float4 for builtins

// Heavy-first segment order (pl=128 first). seg -> v: {6,7,4,5,2,3,0,1}
__device__ __constant__ int c_segv[8]   = {6, 7, 4, 5, 2, 3, 0, 1};
// blocks/seg = 2 col-halves * 32 batches * (n_p/32): 64,64,256,256,256,256,1024,1024
__device__ __constant__ int c_cum[9]    = {0, 64, 128, 384, 640, 896, 1152, 2176, 3200};
__device__ __constant__ int c_lgch[8]   = {0, 0, 2, 2, 2, 2, 4, 4};   // log2(chunks/batch)
// indexed by v:
__device__ __constant__ int c_tokoff[8] = {0, 513, 1026, 1155, 1284, 1413, 1542, 1575};
__device__ __constant__ int c_np[8]     = {512, 512, 128, 128, 128, 128, 32, 32};
__device__ __constant__ int c_pl[8]     = {16, 16, 32, 32, 64, 64, 128, 128};
__device__ __constant__ int c_sf[8]     = {1, 1, 2, 2, 1, 1, 2, 2};
// packed-half2-weight word offsets within d_ws per v; pe occupies words [0,262144)
__device__ __constant__ int c_wtoff[8]  = {262144, 262144, 266240, 266240,
                                           274432, 274432, 290816, 290816};

__device__ __forceinline__ float fdot2f(h2 a, h2 b, float c) {
#if __has_builtin(__builtin_amdgcn_fdot2)
    return __builtin_amdgcn_fdot2(a, b, c, false);
#else
    return fmaf((float)a.y, (float)b.y, fmaf((float)a.x, (float)b.x, c));
#endif
}
__device__ __forceinline__ h2 bch2(unsigned u) { return __builtin_bit_cast(h2, u); }

__device__ __forceinline__ h2 pkrtz(float a, float b) {
#if __has_builtin(__builtin_amdgcn_cvt_pkrtz)
    return __builtin_bit_cast(h2, __builtin_amdgcn_cvt_pkrtz(a, b));
#else
    h2 r; r.x = (_Float16)a; r.y = (_Float16)b; return r;
#endif
}

__device__ __forceinline__ void nt_store4(float* p, float4 v) {
#if __has_builtin(__builtin_nontemporal_store)
    f4n t; t.x = v.x; t.y = v.y; t.z = v.z; t.w = v.w;
    __builtin_nontemporal_store(t, reinterpret_cast<f4n*>(p));
#else
    *reinterpret_cast<float4*>(p) = v;
#endif
}

// ---------------------------------------------------------------------------
// Setup: blocks [0,512) build pe[512][512] fp32 (numpy-matched sinusoidal,
// fast trig: args <= 82 revolutions, err ~5e-5 << 0.137 threshold — validated
// passing in R10); blocks [512,632) pack transposed fp16 weights wt_h[k2][512].
// ---------------------------------------------------------------------------
__global__ __launch_bounds__(512) void setup_kernel(
    const float* __restrict__ w16, const float* __restrict__ w32,
    const float* __restrict__ w64, const float* __restrict__ w128,
    float* __restrict__ ws)
{
    int bid = blockIdx.x;
    int d = threadIdx.x;
    if (bid < 512) {
        int idx = bid * 512 + d;
        int i = idx >> 9;
        int dd = idx & (DM - 1);
        const float c = -9.210340371976184f / 512.0f;  // -ln(10000)/D
        float div = __expf((float)(dd & ~1) * c);
        float ang = (float)i * div;
        ws[idx] = (dd & 1) ? __cosf(ang) : __sinf(ang);
        return;
    }
    int j = bid - 512;                 // 120 half2-rows across the 4 matrices
    const float* w; int pl, k2, off;
    if (j < 8)       { w = w16;  pl = 16;  k2 = j;      off = 262144; }
    else if (j < 24) { w = w32;  pl = 32;  k2 = j - 8;  off = 266240; }
    else if (j < 56) { w = w64;  pl = 64;  k2 = j - 24; off = 274432; }
    else             { w = w128; pl = 128; k2 = j - 56; off = 290816; }
    float2 p = *reinterpret_cast<const float2*>(w + (size_t)d * pl + 2 * k2);
    h2 h; h.x = (_Float16)p.x; h.y = (_Float16)p.y;
    reinterpret_cast<unsigned*>(ws)[off + k2 * DM + d] = __builtin_bit_cast(unsigned, h);
}

// 4-col dot update for row r with patch half2 P and W quad X (cols c0..c0+3)
#define DOT4(r, P, X)                                           \
    acc[r][0] = fdot2f(P, bch2((X).x), acc[r][0]);              \
    acc[r][1] = fdot2f(P, bch2((X).y), acc[r][1]);              \
    acc[r][2] = fdot2f(P, bch2((X).z), acc[r][2]);              \
    acc[r][3] = fdot2f(P, bch2((X).w), acc[r][3]);

// ---------------------------------------------------------------------------
// Main kernel. Blocks [0,3200): 32 rows x 256 cols (col-half h = local&1);
// thread = 8 rows x 4 cols. NO LDS: patch data is wave-uniform, loaded via a
// readfirstlane-uniform pointer (scalarizes to s_load, or degenerates to a
// same-address broadcast L1 vector load — both fine), cvt_pkrtz -> fp16 dot2.
// K loop identical to R7's proven 4-k ping-pong (narrow depth-1 W prefetch).
// Blocks [3200,3208): global-token rows.
// ---------------------------------------------------------------------------
__global__ __launch_bounds__(NTHR, 5) void patch_embed_kernel(
    const float* __restrict__ x,
    const float* __restrict__ b16,  const float* __restrict__ b32,
    const float* __restrict__ b64,  const float* __restrict__ b128,
    const float* __restrict__ glb,  const float* __restrict__ chan,
    const float* __restrict__ ws,   float* __restrict__ out)
{
    int bid = blockIdx.x;
    const int tid = threadIdx.x;

    if (bid >= 3200) {                           // global-token rows (8 blocks)
        int v = bid - 3200;
        int d2 = tid << 1;
        float2 g = *reinterpret_cast<const float2*>(glb + d2);
        float2 c = *reinterpret_cast<const float2*>(chan + v * DM + d2);
        float2 o; o.x = g.x + c.x; o.y = g.y + c.y;
        int row0 = c_tokoff[v] + c_np[v];
        for (int b = 0; b < 32; ++b)
            *reinterpret_cast<float2*>(out + ((size_t)(b * TOK + row0)) * DM + d2) = o;
        return;
    }

    // ---- block -> (v, h, b, chunk), block-uniform scalar work ----
    int seg = 0;
    while (bid >= c_cum[seg + 1]) ++seg;
    int local = bid - c_cum[seg];
    int v = c_segv[seg];
    int h = local & 1;                           // column half
    int rest = local >> 1;
    int lg = c_lgch[seg];
    int b = rest >> lg;
    int chunk = rest & ((1 << lg) - 1);
    const int pl = c_pl[v];
    const int sf = c_sf[v];
    const int pl2 = pl >> 1;
    const int i0 = chunk * BROWS;

    // ---- per-thread / per-wave geometry ----
    const int lane = tid & 63;
    const int wvu  = __builtin_amdgcn_readfirstlane(tid >> 6);  // uniform wave id
    const int c0   = (h << 8) + (lane << 2);     // 4 consecutive cols in half h

    // wave-uniform patch base: rows [i0+8*wvu, +8), elems stride sf in x
    const float* prow_g = x + ((size_t)b * NV + v) * LSEQ
                            + (size_t)(i0 + wvu * 8) * (pl * sf);
    const unsigned* wtv = reinterpret_cast<const unsigned*>(ws) + c_wtoff[v];

    float acc[8][4];
#pragma unroll
    for (int r = 0; r < 8; ++r)
#pragma unroll
        for (int c = 0; c < 4; ++c) acc[r][c] = 0.f;

    // ---- K loop: 4 k per iter; W ping-pong depth-1 (R7's proven pattern) ----
    uint4 w0 = *reinterpret_cast<const uint4*>(wtv + c0);
    uint4 w1 = *reinterpret_cast<const uint4*>(wtv + DM + c0);

    for (int k2 = 0; k2 < pl2; k2 += 2) {
        uint4 n0, n1;
        if (k2 + 2 < pl2) {
            const unsigned* wn = wtv + (size_t)(k2 + 2) * DM;
            n0 = *reinterpret_cast<const uint4*>(wn + c0);
            n1 = *reinterpret_cast<const uint4*>(wn + DM + c0);
        }
        h2 p0[8], p1[8];
        if (sf == 1) {
#pragma unroll
            for (int r = 0; r < 8; ++r) {
                f4n q = *reinterpret_cast<const f4n*>(prow_g + r * pl + 2 * k2);
                p0[r] = pkrtz(q.x, q.y);
                p1[r] = pkrtz(q.z, q.w);
            }
        } else {
#pragma unroll
            for (int r = 0; r < 8; ++r) {
                const float* pb_ = prow_g + r * (pl << 1) + (k2 << 2);
                f4n qa = *reinterpret_cast<const f4n*>(pb_);
                f4n qb = *reinterpret_cast<const f4n*>(pb_ + 4);
                p0[r] = pkrtz(qa.x, qa.z);
                p1[r] = pkrtz(qb.x, qb.z);
            }
        }
#pragma unroll
        for (int r = 0; r < 8; ++r) {
            DOT4(r, p0[r], w0)
            DOT4(r, p1[r], w1)
        }
        w0 = n0; w1 = n1;
    }

    // ---- fp32 epilogue: + bias + channel + pe, nontemporal float4 stores ----
    const float* bias = (pl == 16) ? b16 : (pl == 32) ? b32 : (pl == 64) ? b64 : b128;
    float4 bc;
    {
        float4 ba = *reinterpret_cast<const float4*>(bias + c0);
        float4 ca = *reinterpret_cast<const float4*>(chan + v * DM + c0);
        bc.x = ba.x + ca.x; bc.y = ba.y + ca.y;
        bc.z = ba.z + ca.z; bc.w = ba.w + ca.w;
    }

    const int row0 = i0 + wvu * 8;
    float* ob = out + ((size_t)(b * TOK + c_tokoff[v] + row0)) * DM + c0;
    const float* pb = ws /*pe*/ + (size_t)row0 * DM + c0;
#pragma unroll
    for (int r = 0; r < 8; ++r) {
        float4 pA = *reinterpret_cast<const float4*>(pb + (size_t)r * DM);
        float4 o;
        o.x = acc[r][0] + bc.x + pA.x;
        o.y = acc[r][1] + bc.y + pA.y;
        o.z = acc[r][2] + bc.z + pA.z;
        o.w = acc[r][3] + bc.w + pA.w;
        nt_store4(ob + (size_t)r * DM, o);
    }
}

extern "C" void kernel_launch(void* const* d_in, const int* in_sizes, int n_in,
                              void* d_out, int out_size, void* d_ws, size_t ws_size,
                              hipStream_t stream) {
    const float* x    = (const float*)d_in[0];
    const float* w16  = (const float*)d_in[1];
    const float* b16  = (const float*)d_in[2];
    const float* w32  = (const float*)d_in[3];
    const float* b32  = (const float*)d_in[4];
    const float* w64  = (const float*)d_in[5];
    const float* b64  = (const float*)d_in[6];
    const float* w128 = (const float*)d_in[7];
    const float* b128 = (const float*)d_in[8];
    const float* glb  = (const float*)d_in[9];
    const float* chan = (const float*)d_in[10];
    float* out = (float*)d_out;
    float* ws  = (float*)d_ws;   // pe fp32 [0,262144) + packed fp16 wt -> 1.29 MB

    hipLaunchKernelGGL(setup_kernel, dim3(632), dim3(512), 0, stream,
                       w16, w32, w64, w128, ws);
    hipLaunchKernelGGL(patch_embed_kernel, dim3(3208), dim3(NTHR), 0, stream,
                       x, b16, b32, b64, b128, glb, chan, ws, out);
}

// Round 13
// 38.918 us; speedup vs baseline: 2.9943x; 1.2862x over previous
//
#include <hip/hip_runtime.h>
#include <math.h>

#define DM 512
#define LSEQ 8192
#define NV 8
#define TOK 1608
#define BROWS 32     // patch rows per block
#define NTHR 256     // 4 waves; wave = 8 rows x 256 cols; thread = 8r x 4c

typedef _Float16 h2 __attribute__((ext_vector_type(2)));
typedef float f4n __attribute__((ext_vector_type(4)));   // native float4 for builtins

// Heavy-first segment order (pl=128 first). seg -> v: {6,7,4,5,2,3,0,1}
__device__ __constant__ int c_segv[8]   = {6, 7, 4, 5, 2, 3, 0, 1};
// blocks/seg = 2 col-halves * 32 batches * (n_p/32): 64,64,256,256,256,256,1024,1024
__device__ __constant__ int c_cum[9]    = {0, 64, 128, 384, 640, 896, 1152, 2176, 3200};
__device__ __constant__ int c_lgch[8]   = {0, 0, 2, 2, 2, 2, 4, 4};   // log2(chunks/batch)
// indexed by v:
__device__ __constant__ int c_tokoff[8] = {0, 513, 1026, 1155, 1284, 1413, 1542, 1575};
__device__ __constant__ int c_np[8]     = {512, 512, 128, 128, 128, 128, 32, 32};
__device__ __constant__ int c_pl[8]     = {16, 16, 32, 32, 64, 64, 128, 128};
__device__ __constant__ int c_sf[8]     = {1, 1, 2, 2, 1, 1, 2, 2};
// packed-half2-weight word offsets within d_ws per v; pe occupies words [0,262144)
__device__ __constant__ int c_wtoff[8]  = {262144, 262144, 266240, 266240,
                                           274432, 274432, 290816, 290816};

__device__ __forceinline__ float fdot2f(h2 a, h2 b, float c) {
#if __has_builtin(__builtin_amdgcn_fdot2)
    return __builtin_amdgcn_fdot2(a, b, c, false);
#else
    return fmaf((float)a.y, (float)b.y, fmaf((float)a.x, (float)b.x, c));
#endif
}
__device__ __forceinline__ h2 bch2(unsigned u) { return __builtin_bit_cast(h2, u); }

__device__ __forceinline__ void nt_store4(float* p, float4 v) {
#if __has_builtin(__builtin_nontemporal_store)
    f4n t; t.x = v.x; t.y = v.y; t.z = v.z; t.w = v.w;
    __builtin_nontemporal_store(t, reinterpret_cast<f4n*>(p));
#else
    *reinterpret_cast<float4*>(p) = v;
#endif
}

// ---------------------------------------------------------------------------
// Setup: blocks [0,512) build pe[512][512] fp32 (numpy-matched sinusoidal,
// fast trig validated in R10/R12: absmax unchanged); blocks [512,632) pack
// transposed fp16 weights wt_h[k2][512] (half2 words).
// ---------------------------------------------------------------------------
__global__ __launch_bounds__(512) void setup_kernel(
    const float* __restrict__ w16, const float* __restrict__ w32,
    const float* __restrict__ w64, const float* __restrict__ w128,
    float* __restrict__ ws)
{
    int bid = blockIdx.x;
    int d = threadIdx.x;
    if (bid < 512) {
        int idx = bid * 512 + d;
        int i = idx >> 9;
        int dd = idx & (DM - 1);
        const float c = -9.210340371976184f / 512.0f;  // -ln(10000)/D
        float div = __expf((float)(dd & ~1) * c);
        float ang = (float)i * div;
        ws[idx] = (dd & 1) ? __cosf(ang) : __sinf(ang);
        return;
    }
    int j = bid - 512;                 // 120 half2-rows across the 4 matrices
    const float* w; int pl, k2, off;
    if (j < 8)       { w = w16;  pl = 16;  k2 = j;      off = 262144; }
    else if (j < 24) { w = w32;  pl = 32;  k2 = j - 8;  off = 266240; }
    else if (j < 56) { w = w64;  pl = 64;  k2 = j - 24; off = 274432; }
    else             { w = w128; pl = 128; k2 = j - 56; off = 290816; }
    float2 p = *reinterpret_cast<const float2*>(w + (size_t)d * pl + 2 * k2);
    h2 h; h.x = (_Float16)p.x; h.y = (_Float16)p.y;
    reinterpret_cast<unsigned*>(ws)[off + k2 * DM + d] = __builtin_bit_cast(unsigned, h);
}

// 4-col dot update for row r with patch half2 P and W quad X (cols c0..c0+3)
#define DOT4(r, P, X)                                           \
    acc[r][0] = fdot2f(P, bch2((X).x), acc[r][0]);              \
    acc[r][1] = fdot2f(P, bch2((X).y), acc[r][1]);              \
    acc[r][2] = fdot2f(P, bch2((X).z), acc[r][2]);              \
    acc[r][3] = fdot2f(P, bch2((X).w), acc[r][3]);

// ---------------------------------------------------------------------------
// Main kernel. Blocks [0,3200): 32 rows x 256 cols (col-half h = local&1);
// thread = 8 rows x 4 cols, fp16 dot2, fp32 epilogue. [3200,3208): global toks.
// K loop: 8-k iterations; per row ONE ds_read_b128 (vs 2x b64) halves LDS
// instruction count; W pairs stay 8-reg narrow with ~192-cyc lookahead
// (pair-B loads before half-A dots; pair-A' before half-B dots).
// Peak live regs ~98 <= 102 cap of (256,5) -> no spill by design.
// ---------------------------------------------------------------------------
__global__ __launch_bounds__(NTHR, 5) void patch_embed_kernel(
    const float* __restrict__ x,
    const float* __restrict__ b16,  const float* __restrict__ b32,
    const float* __restrict__ b64,  const float* __restrict__ b128,
    const float* __restrict__ glb,  const float* __restrict__ chan,
    const float* __restrict__ ws,   float* __restrict__ out)
{
    extern __shared__ float ldsf[];              // 32 rows * pl/2 half2 words, <= 8 KB
    unsigned* ldsu = reinterpret_cast<unsigned*>(ldsf);
    int bid = blockIdx.x;
    const int tid = threadIdx.x;

    if (bid >= 3200) {                           // global-token rows (8 blocks)
        int v = bid - 3200;
        int d2 = tid << 1;
        float2 g = *reinterpret_cast<const float2*>(glb + d2);
        float2 c = *reinterpret_cast<const float2*>(chan + v * DM + d2);
        float2 o; o.x = g.x + c.x; o.y = g.y + c.y;
        int row0 = c_tokoff[v] + c_np[v];
        for (int b = 0; b < 32; ++b)
            *reinterpret_cast<float2*>(out + ((size_t)(b * TOK + row0)) * DM + d2) = o;
        return;
    }

    // ---- block -> (v, h, b, chunk), block-uniform scalar work ----
    int seg = 0;
    while (bid >= c_cum[seg + 1]) ++seg;
    int local = bid - c_cum[seg];
    int v = c_segv[seg];
    int h = local & 1;                           // column half
    int rest = local >> 1;
    int lg = c_lgch[seg];
    int b = rest >> lg;
    int chunk = rest & ((1 << lg) - 1);
    const int pl = c_pl[v];
    const int sf = c_sf[v];
    const int pl2 = pl >> 1;
    const int i0 = chunk * BROWS;

    // ---- stage 32 packed patches into LDS as half2 (sampling folded) ----
    const int ne2 = (BROWS * pl) >> 1;           // half2 words
    const float* xb = x + ((size_t)b * NV + v) * LSEQ + (size_t)i0 * (pl * sf);
    if (sf == 1) {
        for (int t = tid; t < (ne2 >> 1); t += NTHR) {   // t = one float4 = 2 words
            float4 q = *reinterpret_cast<const float4*>(xb + 4 * t);
            h2 a; a.x = (_Float16)q.x; a.y = (_Float16)q.y;
            h2 c; c.x = (_Float16)q.z; c.y = (_Float16)q.w;
            uint2 o; o.x = __builtin_bit_cast(unsigned, a);
            o.y = __builtin_bit_cast(unsigned, c);
            *reinterpret_cast<uint2*>(ldsu + 2 * t) = o;
        }
    } else {
        for (int p = tid; p < ne2; p += NTHR) {          // one word per float4
            float4 q = *reinterpret_cast<const float4*>(xb + 4 * p);
            h2 a; a.x = (_Float16)q.x; a.y = (_Float16)q.z;
            ldsu[p] = __builtin_bit_cast(unsigned, a);
        }
    }
    __syncthreads();

    // ---- per-thread geometry ----
    const int lane = tid & 63;
    const int wv   = tid >> 6;                   // wave -> rows [8wv, 8wv+8)
    const int c0   = (h << 8) + (lane << 2);     // 4 consecutive cols in half h
    const unsigned* prow = ldsu + (wv * 8) * pl2;
    const unsigned* wtv  = reinterpret_cast<const unsigned*>(ws) + c_wtoff[v];

    float acc[8][4];
#pragma unroll
    for (int r = 0; r < 8; ++r)
#pragma unroll
        for (int c = 0; c < 4; ++c) acc[r][c] = 0.f;

    // ---- K loop: 8 k (4 k2-rows) per iter ----
    uint4 wA0 = *reinterpret_cast<const uint4*>(wtv + c0);        // k2-row 0
    uint4 wA1 = *reinterpret_cast<const uint4*>(wtv + DM + c0);   // k2-row 1

    for (int k2 = 0; k2 < pl2; k2 += 4) {
        // patch quads: 8 rows x 4 k2 (8 k) — one b128 broadcast per row
        uint4 pr[8];
#pragma unroll
        for (int r = 0; r < 8; ++r)
            pr[r] = *reinterpret_cast<const uint4*>(prow + r * pl2 + k2);

        // pair B (k2-rows +2, +3) — consumed after half-A's 128 cyc of dots
        const unsigned* wb_ = wtv + (size_t)(k2 + 2) * DM;
        uint4 wB0 = *reinterpret_cast<const uint4*>(wb_ + c0);
        uint4 wB1 = *reinterpret_cast<const uint4*>(wb_ + DM + c0);

        // half A: k2, k2+1
#pragma unroll
        for (int r = 0; r < 8; ++r) {
            DOT4(r, bch2(pr[r].x), wA0)
            DOT4(r, bch2(pr[r].y), wA1)
        }

        // pair A' (k2-rows +4, +5) — consumed after half-B's 128 cyc of dots
        uint4 nA0, nA1;
        const bool more = (k2 + 4 < pl2);
        if (more) {
            const unsigned* wa_ = wtv + (size_t)(k2 + 4) * DM;
            nA0 = *reinterpret_cast<const uint4*>(wa_ + c0);
            nA1 = *reinterpret_cast<const uint4*>(wa_ + DM + c0);
        }

        // half B: k2+2, k2+3
#pragma unroll
        for (int r = 0; r < 8; ++r) {
            DOT4(r, bch2(pr[r].z), wB0)
            DOT4(r, bch2(pr[r].w), wB1)
        }

        if (more) { wA0 = nA0; wA1 = nA1; }
    }

    // ---- fp32 epilogue: + bias + channel + pe, nontemporal float4 stores ----
    const float* bias = (pl == 16) ? b16 : (pl == 32) ? b32 : (pl == 64) ? b64 : b128;
    float4 bc;
    {
        float4 ba = *reinterpret_cast<const float4*>(bias + c0);
        float4 ca = *reinterpret_cast<const float4*>(chan + v * DM + c0);
        bc.x = ba.x + ca.x; bc.y = ba.y + ca.y;
        bc.z = ba.z + ca.z; bc.w = ba.w + ca.w;
    }

    const int row0 = i0 + wv * 8;
    float* ob = out + ((size_t)(b * TOK + c_tokoff[v] + row0)) * DM + c0;
    const float* pb = ws /*pe*/ + (size_t)row0 * DM + c0;
#pragma unroll
    for (int r = 0; r < 8; ++r) {
        float4 pA = *reinterpret_cast<const float4*>(pb + (size_t)r * DM);
        float4 o;
        o.x = acc[r][0] + bc.x + pA.x;
        o.y = acc[r][1] + bc.y + pA.y;
        o.z = acc[r][2] + bc.z + pA.z;
        o.w = acc[r][3] + bc.w + pA.w;
        nt_store4(ob + (size_t)r * DM, o);
    }
}

extern "C" void kernel_launch(void* const* d_in, const int* in_sizes, int n_in,
                              void* d_out, int out_size, void* d_ws, size_t ws_size,
                              hipStream_t stream) {
    const float* x    = (const float*)d_in[0];
    const float* w16  = (const float*)d_in[1];
    const float* b16  = (const float*)d_in[2];
    const float* w32  = (const float*)d_in[3];
    const float* b32  = (const float*)d_in[4];
    const float* w64  = (const float*)d_in[5];
    const float* b64  = (const float*)d_in[6];
    const float* w128 = (const float*)d_in[7];
    const float* b128 = (const float*)d_in[8];
    const float* glb  = (const float*)d_in[9];
    const float* chan = (const float*)d_in[10];
    float* out = (float*)d_out;
    float* ws  = (float*)d_ws;   // pe fp32 [0,262144) + packed fp16 wt -> 1.29 MB

    hipLaunchKernelGGL(setup_kernel, dim3(632), dim3(512), 0, stream,
                       w16, w32, w64, w128, ws);
    hipLaunchKernelGGL(patch_embed_kernel, dim3(3208), dim3(NTHR),
                       BROWS * 64 * sizeof(unsigned),   // 8 KB dynamic LDS (pl=128)
                       stream,
                       x, b16, b32, b64, b128, glb, chan, ws, out);
}

// Round 14
// 37.863 us; speedup vs baseline: 3.0778x; 1.0279x over previous
//
#include <hip/hip_runtime.h>
#include <math.h>

#define DM 512
#define LSEQ 8192
#define NV 8
#define TOK 1608
#define BROWS 32     // patch rows per block
#define NTHR 256     // 4 waves; wave = 8 rows x 256 cols; thread = 8r x 4c

typedef _Float16 h2 __attribute__((ext_vector_type(2)));
typedef float f4n __attribute__((ext_vector_type(4)));   // native float4 for builtins

// Heavy-first segment order (pl=128 first). seg -> v: {6,7,4,5,2,3,0,1}
__device__ __constant__ int c_segv[8]   = {6, 7, 4, 5, 2, 3, 0, 1};
// blocks/seg = 2 col-halves * 32 batches * (n_p/32): 64,64,256,256,256,256,1024,1024
__device__ __constant__ int c_cum[9]    = {0, 64, 128, 384, 640, 896, 1152, 2176, 3200};
__device__ __constant__ int c_lgch[8]   = {0, 0, 2, 2, 2, 2, 4, 4};   // log2(chunks/batch)
// indexed by v:
__device__ __constant__ int c_tokoff[8] = {0, 513, 1026, 1155, 1284, 1413, 1542, 1575};
__device__ __constant__ int c_np[8]     = {512, 512, 128, 128, 128, 128, 32, 32};
__device__ __constant__ int c_pl[8]     = {16, 16, 32, 32, 64, 64, 128, 128};
__device__ __constant__ int c_sf[8]     = {1, 1, 2, 2, 1, 1, 2, 2};
// packed-half2-weight word offsets within d_ws per v (pe table removed):
// w16@0 (8 k2-rows), w32@4096 (16), w64@12288 (32), w128@28672 (64)
__device__ __constant__ int c_wtoff[8]  = {0, 0, 4096, 4096, 12288, 12288, 28672, 28672};

__device__ __forceinline__ float fdot2f(h2 a, h2 b, float c) {
#if __has_builtin(__builtin_amdgcn_fdot2)
    return __builtin_amdgcn_fdot2(a, b, c, false);
#else
    return fmaf((float)a.y, (float)b.y, fmaf((float)a.x, (float)b.x, c));
#endif
}
__device__ __forceinline__ h2 bch2(unsigned u) { return __builtin_bit_cast(h2, u); }

__device__ __forceinline__ void nt_store4(float* p, float4 v) {
#if __has_builtin(__builtin_nontemporal_store)
    f4n t; t.x = v.x; t.y = v.y; t.z = v.z; t.w = v.w;
    __builtin_nontemporal_store(t, reinterpret_cast<f4n*>(p));
#else
    *reinterpret_cast<float4*>(p) = v;
#endif
}

// ---------------------------------------------------------------------------
// Setup: 120 blocks pack transposed fp16 weights wt_h[k2][512] (half2 words).
// (pe table is now computed inline in the main kernel's epilogue.)
// ---------------------------------------------------------------------------
__global__ __launch_bounds__(512) void setup_kernel(
    const float* __restrict__ w16, const float* __restrict__ w32,
    const float* __restrict__ w64, const float* __restrict__ w128,
    float* __restrict__ ws)
{
    int j = blockIdx.x;                // 120 half2-rows across the 4 matrices
    int d = threadIdx.x;
    const float* w; int pl, k2, off;
    if (j < 8)       { w = w16;  pl = 16;  k2 = j;      off = 0; }
    else if (j < 24) { w = w32;  pl = 32;  k2 = j - 8;  off = 4096; }
    else if (j < 56) { w = w64;  pl = 64;  k2 = j - 24; off = 12288; }
    else             { w = w128; pl = 128; k2 = j - 56; off = 28672; }
    float2 p = *reinterpret_cast<const float2*>(w + (size_t)d * pl + 2 * k2);
    h2 h; h.x = (_Float16)p.x; h.y = (_Float16)p.y;
    reinterpret_cast<unsigned*>(ws)[off + k2 * DM + d] = __builtin_bit_cast(unsigned, h);
}

// 4-col dot update for row r with patch half2 P and W quad X (cols c0..c0+3)
#define DOT4(r, P, X)                                           \
    acc[r][0] = fdot2f(P, bch2((X).x), acc[r][0]);              \
    acc[r][1] = fdot2f(P, bch2((X).y), acc[r][1]);              \
    acc[r][2] = fdot2f(P, bch2((X).z), acc[r][2]);              \
    acc[r][3] = fdot2f(P, bch2((X).w), acc[r][3]);

// ---------------------------------------------------------------------------
// Main kernel. Blocks [0,3200): 32 rows x 256 cols (col-half h = local&1);
// thread = 8 rows x 4 cols, fp16 dot2, fp32 epilogue with INLINE sinusoidal
// pe (fast trig, args <= 82 revolutions — accuracy validated R10/R12/R13).
// K loop byte-identical to R7's proven 4-k narrow ping-pong.
// Blocks [3200,3208): global-token rows.
// ---------------------------------------------------------------------------
__global__ __launch_bounds__(NTHR, 6) void patch_embed_kernel(
    const float* __restrict__ x,
    const float* __restrict__ b16,  const float* __restrict__ b32,
    const float* __restrict__ b64,  const float* __restrict__ b128,
    const float* __restrict__ glb,  const float* __restrict__ chan,
    const float* __restrict__ ws,   float* __restrict__ out)
{
    extern __shared__ float ldsf[];              // 32 rows * pl/2 half2 words, <= 8 KB
    unsigned* ldsu = reinterpret_cast<unsigned*>(ldsf);
    int bid = blockIdx.x;
    const int tid = threadIdx.x;

    if (bid >= 3200) {                           // global-token rows (8 blocks)
        int v = bid - 3200;
        int d2 = tid << 1;
        float2 g = *reinterpret_cast<const float2*>(glb + d2);
        float2 c = *reinterpret_cast<const float2*>(chan + v * DM + d2);
        float2 o; o.x = g.x + c.x; o.y = g.y + c.y;
        int row0 = c_tokoff[v] + c_np[v];
        for (int b = 0; b < 32; ++b)
            *reinterpret_cast<float2*>(out + ((size_t)(b * TOK + row0)) * DM + d2) = o;
        return;
    }

    // ---- block -> (v, h, b, chunk), block-uniform scalar work ----
    int seg = 0;
    while (bid >= c_cum[seg + 1]) ++seg;
    int local = bid - c_cum[seg];
    int v = c_segv[seg];
    int h = local & 1;                           // column half
    int rest = local >> 1;
    int lg = c_lgch[seg];
    int b = rest >> lg;
    int chunk = rest & ((1 << lg) - 1);
    const int pl = c_pl[v];
    const int sf = c_sf[v];
    const int pl2 = pl >> 1;
    const int i0 = chunk * BROWS;

    // ---- stage 32 packed patches into LDS as half2 (sampling folded) ----
    const int ne2 = (BROWS * pl) >> 1;           // half2 words
    const float* xb = x + ((size_t)b * NV + v) * LSEQ + (size_t)i0 * (pl * sf);
    if (sf == 1) {
        for (int t = tid; t < (ne2 >> 1); t += NTHR) {   // t = one float4 = 2 words
            float4 q = *reinterpret_cast<const float4*>(xb + 4 * t);
            h2 a; a.x = (_Float16)q.x; a.y = (_Float16)q.y;
            h2 c; c.x = (_Float16)q.z; c.y = (_Float16)q.w;
            uint2 o; o.x = __builtin_bit_cast(unsigned, a);
            o.y = __builtin_bit_cast(unsigned, c);
            *reinterpret_cast<uint2*>(ldsu + 2 * t) = o;
        }
    } else {
        for (int p = tid; p < ne2; p += NTHR) {          // one word per float4
            float4 q = *reinterpret_cast<const float4*>(xb + 4 * p);
            h2 a; a.x = (_Float16)q.x; a.y = (_Float16)q.z;
            ldsu[p] = __builtin_bit_cast(unsigned, a);
        }
    }
    __syncthreads();

    // ---- per-thread geometry ----
    const int lane = tid & 63;
    const int wv   = tid >> 6;                   // wave -> rows [8wv, 8wv+8)
    const int c0   = (h << 8) + (lane << 2);     // 4 consecutive cols (c0 even)
    const unsigned* prow = ldsu + (wv * 8) * pl2;
    const unsigned* wtv  = reinterpret_cast<const unsigned*>(ws) + c_wtoff[v];

    float acc[8][4];
#pragma unroll
    for (int r = 0; r < 8; ++r)
#pragma unroll
        for (int c = 0; c < 4; ++c) acc[r][c] = 0.f;

    // ---- K loop: 4 k per iter; W ping-pong depth-1 (R7's proven pattern) ----
    uint4 w0 = *reinterpret_cast<const uint4*>(wtv + c0);
    uint4 w1 = *reinterpret_cast<const uint4*>(wtv + DM + c0);

    for (int k2 = 0; k2 < pl2; k2 += 2) {
        uint4 n0, n1;
        if (k2 + 2 < pl2) {
            const unsigned* wn = wtv + (size_t)(k2 + 2) * DM;
            n0 = *reinterpret_cast<const uint4*>(wn + c0);
            n1 = *reinterpret_cast<const uint4*>(wn + DM + c0);
        }
        uint2 pr[8];
#pragma unroll
        for (int r = 0; r < 8; ++r)
            pr[r] = *reinterpret_cast<const uint2*>(prow + r * pl2 + k2);
#pragma unroll
        for (int r = 0; r < 8; ++r) {
            DOT4(r, bch2(pr[r].x), w0)
            DOT4(r, bch2(pr[r].y), w1)
        }
        w0 = n0; w1 = n1;
    }

    // ---- fp32 epilogue: + bias + channel + inline pe, nontemporal stores ----
    const float* bias = (pl == 16) ? b16 : (pl == 32) ? b32 : (pl == 64) ? b64 : b128;
    float4 bc;
    {
        float4 ba = *reinterpret_cast<const float4*>(bias + c0);
        float4 ca = *reinterpret_cast<const float4*>(chan + v * DM + c0);
        bc.x = ba.x + ca.x; bc.y = ba.y + ca.y;
        bc.z = ba.z + ca.z; bc.w = ba.w + ca.w;
    }

    // pe(i, d): j = d&~1; pe = sin/cos(i * exp(j * -ln(1e4)/512))
    const float kc_ = -9.210340371976184f / 512.0f;
    const float div0 = __expf((float)c0 * kc_);          // cols c0, c0+1
    const float div2 = __expf((float)(c0 + 2) * kc_);    // cols c0+2, c0+3

    const int row0 = i0 + wv * 8;
    float* ob = out + ((size_t)(b * TOK + c_tokoff[v] + row0)) * DM + c0;
#pragma unroll
    for (int r = 0; r < 8; ++r) {
        float fi = (float)(row0 + r);
        float a0 = fi * div0;
        float a2 = fi * div2;
        float4 o;
        o.x = acc[r][0] + bc.x + __sinf(a0);
        o.y = acc[r][1] + bc.y + __cosf(a0);
        o.z = acc[r][2] + bc.z + __sinf(a2);
        o.w = acc[r][3] + bc.w + __cosf(a2);
        nt_store4(ob + (size_t)r * DM, o);
    }
}

extern "C" void kernel_launch(void* const* d_in, const int* in_sizes, int n_in,
                              void* d_out, int out_size, void* d_ws, size_t ws_size,
                              hipStream_t stream) {
    const float* x    = (const float*)d_in[0];
    const float* w16  = (const float*)d_in[1];
    const float* b16  = (const float*)d_in[2];
    const float* w32  = (const float*)d_in[3];
    const float* b32  = (const float*)d_in[4];
    const float* w64  = (const float*)d_in[5];
    const float* b64  = (const float*)d_in[6];
    const float* w128 = (const float*)d_in[7];
    const float* b128 = (const float*)d_in[8];
    const float* glb  = (const float*)d_in[9];
    const float* chan = (const float*)d_in[10];
    float* out = (float*)d_out;
    float* ws  = (float*)d_ws;   // packed fp16 wt only -> 240 KB

    hipLaunchKernelGGL(setup_kernel, dim3(120), dim3(512), 0, stream,
                       w16, w32, w64, w128, ws);
    hipLaunchKernelGGL(patch_embed_kernel, dim3(3208), dim3(NTHR),
                       BROWS * 64 * sizeof(unsigned),   // 8 KB dynamic LDS (pl=128)
                       stream,
                       x, b16, b32, b64, b128, glb, chan, ws, out);
}